// Round 1
// baseline (91.548 us; speedup 1.0000x reference)
//
#include <hip/hip_runtime.h>

typedef float2 cplx;

__device__ __forceinline__ cplx cmul(cplx a, cplx b){
  return make_float2(a.x*b.x - a.y*b.y, a.x*b.y + a.y*b.x);
}
__device__ __forceinline__ cplx cmad(cplx a, cplx b, cplx acc){  // acc + a*b
  return make_float2(acc.x + a.x*b.x - a.y*b.y, acc.y + a.x*b.y + a.y*b.x);
}

// ======================= setup kernel (unchanged, verified R1) =======================
__device__ __forceinline__ void rz_gate(cplx* st, float t, int bmask){
  float s, c; sincosf(0.5f*t, &s, &c);
  cplx em = make_float2(c, -s), ep = make_float2(c, s);
  for(int k=0;k<4;k++) st[k] = cmul(st[k], (k & bmask) ? ep : em);
}
__device__ __forceinline__ void ry_gate_q(cplx* st, float t){
  float s, c; sincosf(0.5f*t, &s, &c);
  for(int bp=0;bp<2;bp++){
    cplx a0 = st[bp], a1 = st[2+bp];
    st[bp]   = make_float2(c*a0.x - s*a1.x, c*a0.y - s*a1.y);
    st[2+bp] = make_float2(s*a0.x + c*a1.x, s*a0.y + c*a1.y);
  }
}
__device__ __forceinline__ void u3_gate(cplx* st, const float* p, int onq){
  float th=p[0], ph=p[1], la=p[2];
  float ss,cc,sl,cl,sp,cp,spl,cpl;
  sincosf(0.5f*th,&ss,&cc); sincosf(la,&sl,&cl); sincosf(ph,&sp,&cp); sincosf(ph+la,&spl,&cpl);
  cplx u00=make_float2(cc,0.f), u01=make_float2(-cl*ss,-sl*ss);
  cplx u10=make_float2(cp*ss,sp*ss), u11=make_float2(cpl*cc,spl*cc);
  if(onq){
    for(int bp=0;bp<2;bp++){
      cplx a0=st[bp], a1=st[2+bp];
      st[bp]   = cmad(u01,a1,cmul(u00,a0));
      st[2+bp] = cmad(u11,a1,cmul(u10,a0));
    }
  } else {
    for(int bq=0;bq<2;bq++){
      cplx a0=st[2*bq], a1=st[2*bq+1];
      st[2*bq]   = cmad(u01,a1,cmul(u00,a0));
      st[2*bq+1] = cmad(u11,a1,cmul(u10,a0));
    }
  }
}

__global__ void setup_conv_kernel(const float* __restrict__ rz,
                                  const float* __restrict__ ry,
                                  const float* __restrict__ u3,
                                  cplx* __restrict__ M){
  int t = threadIdx.x;
  if(t >= 28) return;
  int ci = t >> 2, col = t & 3;
  const float* rz3 = rz + 3*ci;
  const float* ry2 = ry + 2*ci;
  int u3slot = 0, u3idx = 0;
  if(ci <= 3){ u3slot = 1; u3idx = ci; }
  else if(ci == 5){ u3slot = 1; u3idx = 5; }
  else if(ci == 6){ u3slot = 2; u3idx = 4; }
  cplx st[4];
  for(int k=0;k<4;k++) st[k] = make_float2(k==col ? 1.f : 0.f, 0.f);
  rz_gate(st, rz3[0], 2);
  { cplx tmp=st[2]; st[2]=st[3]; st[3]=tmp; }
  rz_gate(st, rz3[1], 1);
  ry_gate_q(st, ry2[0]);
  { cplx tmp=st[1]; st[1]=st[3]; st[3]=tmp; }
  ry_gate_q(st, ry2[1]);
  { cplx tmp=st[2]; st[2]=st[3]; st[3]=tmp; }
  rz_gate(st, rz3[2], 1);
  if(u3slot == 1)      u3_gate(st, u3+3*u3idx, 1);
  else if(u3slot == 2) u3_gate(st, u3+3*u3idx, 0);
  for(int k=0;k<4;k++) M[ci*16 + k*4 + col] = st[k];
}

// ======================= main kernel =======================
// 16 amplitudes per lane, 16 lanes per element, 4 elements per wave.
// Amplitude i[7:0]; wire w <-> bit (7-w).
// Register index r[3:0] = i[7:4]  (wires 0,1,2,3 -> reg masks 8,4,2,1)
// Sublane s[3:0]: s0=wire4(i3), s1=wire5(i2), s2=wire6(i1), s3=wire7(i0)
//   -> lane xor masks: w4=1, w5=2, w6=4, w7=8
// DPP (VALU pipe): masks 1 (quad xor1), 2 (xor2), 3 (xor3), 8 (row_ror:8)
// ds_swizzle (LDS pipe): masks 4, 6, 10, 12

#define DPP_XOR1 0xB1   // quad_perm [1,0,3,2]
#define DPP_XOR2 0x4E   // quad_perm [2,3,0,1]
#define DPP_XOR3 0x1B   // quad_perm [3,2,1,0]
#define DPP_ROR8 0x128  // row_ror:8 == xor 8 within 16-lane row

template<int C>
__device__ __forceinline__ float xdpp(float x){
  return __builtin_bit_cast(float,
    __builtin_amdgcn_mov_dpp(__builtin_bit_cast(int, x), C, 0xF, 0xF, true));
}
template<int MASK>
__device__ __forceinline__ float xswz(float x){
  return __builtin_bit_cast(float,
    __builtin_amdgcn_ds_swizzle(__builtin_bit_cast(int, x), (MASK<<10) | 0x1F));
}

enum Sh { SH_DPP1, SH_DPP2, SH_DPP3, SH_ROR8, SH_SWZ4, SH_SWZ6, SH_SWZ10, SH_SWZ12 };

template<Sh S> __device__ __forceinline__ float shf(float x){
  if      constexpr(S==SH_DPP1)  return xdpp<DPP_XOR1>(x);
  else if constexpr(S==SH_DPP2)  return xdpp<DPP_XOR2>(x);
  else if constexpr(S==SH_DPP3)  return xdpp<DPP_XOR3>(x);
  else if constexpr(S==SH_ROR8)  return xdpp<DPP_ROR8>(x);
  else if constexpr(S==SH_SWZ4)  return xswz<4>(x);
  else if constexpr(S==SH_SWZ6)  return xswz<6>(x);
  else if constexpr(S==SH_SWZ10) return xswz<10>(x);
  else                           return xswz<12>(x);
}
template<Sh S> __device__ __forceinline__ cplx shc(cplx a){
  return make_float2(shf<S>(a.x), shf<S>(a.y));
}

// rxx: new = c*psi - i*s*partner  -> x' = c*x + s*p.y ; y' = c*y - s*p.x
template<int MR>
__device__ __forceinline__ void rxx_reg(cplx* v, float c, float s){
  #pragma unroll
  for(int r=0;r<16;r++){
    int q = r ^ MR;
    if(r > q) continue;
    cplx a = v[r], b = v[q];
    v[r] = make_float2(c*a.x + s*b.y, c*a.y - s*b.x);
    v[q] = make_float2(c*b.x + s*a.y, c*b.y - s*a.x);
  }
}
template<Sh S>
__device__ __forceinline__ void rxx_lane(cplx* v, float c, float s){
  #pragma unroll
  for(int r=0;r<16;r++){
    cplx p = shc<S>(v[r]);
    v[r] = make_float2(c*v[r].x + s*p.y, c*v[r].y - s*p.x);
  }
}
// pair (3,4): reg mask 1 + lane xor1
__device__ __forceinline__ void rxx_mix34(cplx* v, float c, float s){
  #pragma unroll
  for(int r=0;r<16;r+=2){
    cplx pa = shc<SH_DPP1>(v[r^1]);
    cplx pb = shc<SH_DPP1>(v[r]);
    cplx a = v[r], b = v[r^1];
    v[r]   = make_float2(c*a.x + s*pa.y, c*a.y - s*pa.x);
    v[r^1] = make_float2(c*b.x + s*pb.y, c*b.y - s*pb.x);
  }
}

// conv on two register wires: group {r, r^MP, r^MQ, r^MQ^MP} = columns 0..3
template<int MQ, int MP>
__device__ __forceinline__ void conv_reg(cplx* v, const cplx* __restrict__ M){
  #pragma unroll
  for(int r=0;r<16;r++){
    if((r & (MQ|MP)) != 0) continue;
    cplx a0=v[r], a1=v[r^MP], a2=v[r^MQ], a3=v[r^MQ^MP];
    v[r]        = cmad(M[3], a3, cmad(M[2], a2, cmad(M[1], a1, cmul(M[0], a0))));
    v[r^MP]     = cmad(M[7], a3, cmad(M[6], a2, cmad(M[5], a1, cmul(M[4], a0))));
    v[r^MQ]     = cmad(M[11],a3, cmad(M[10],a2, cmad(M[9], a1, cmul(M[8], a0))));
    v[r^MQ^MP]  = cmad(M[15],a3, cmad(M[14],a2, cmad(M[13],a1, cmul(M[12],a0))));
  }
}

// conv on two lane wires; k = 2*bit_q + bit_p (per-lane, r-independent)
template<Sh SQ, Sh SP, Sh SB>
__device__ __forceinline__ void conv_lane(cplx* v, const cplx* __restrict__ M, int k){
  cplx es = M[k*4 + k], ep = M[k*4 + (k^1)], eq = M[k*4 + (k^2)], eb = M[k*4 + (k^3)];
  #pragma unroll
  for(int r=0;r<16;r++){
    cplx pq = shc<SQ>(v[r]);
    cplx pp = shc<SP>(v[r]);
    cplx pb = shc<SB>(v[r]);
    v[r] = cmad(eb, pb, cmad(eq, pq, cmad(ep, pp, cmul(es, v[r]))));
  }
}

// conv (5,3): q = wire5 (lane s1, xor2 DPP), p = wire3 (reg bit 0)
__device__ __forceinline__ void conv_53(cplx* v, const cplx* __restrict__ M, int s1){
  int t = 2*s1, u = 2 - t;
  const cplx* r0 = M + t*4;        // row k = t   (held bp=0)
  const cplx* r1 = M + (t+1)*4;    // row k = t+1 (held bp=1)
  cplx e00=r0[t], e01=r0[t+1], e02=r0[u], e03=r0[u+1];
  cplx e10=r1[t], e11=r1[t+1], e12=r1[u], e13=r1[u+1];
  #pragma unroll
  for(int r=0;r<16;r+=2){
    cplx pv0 = shc<SH_DPP2>(v[r]);     // partner (q flipped) of bp=0
    cplx pv1 = shc<SH_DPP2>(v[r+1]);   // partner of bp=1
    cplx a0 = v[r], a1 = v[r+1];
    v[r]   = cmad(e03, pv1, cmad(e02, pv0, cmad(e01, a1, cmul(e00, a0))));
    v[r+1] = cmad(e13, pv1, cmad(e12, pv0, cmad(e11, a1, cmul(e10, a0))));
  }
}

__global__ void __launch_bounds__(256) qcnn_kernel(
    const float* __restrict__ theta, const float* __restrict__ phi,
    const cplx* __restrict__ Mg,
    const float* __restrict__ w1, const float* __restrict__ b1,
    const float* __restrict__ w2, const float* __restrict__ b2,
    float* __restrict__ out){
  int tid  = threadIdx.x;
  int s_   = tid & 15;                       // sublane within element (DPP-row aligned)
  int b    = blockIdx.x*16 + (tid >> 4);     // element id
  int s0 = s_&1, s1 = (s_>>1)&1, s2 = (s_>>2)&1, s3 = (s_>>3)&1;

  float th = theta[b], ph = phi[b];
  float c, s;
  __sincosf(th, &s, &c);

  // zphase factors: cis(phi*(2*(popc(s)+popc(r)) - 8)), popc(r) in 0..4
  cplx zp[5];
  {
    int base = __popc(s_);
    float a0 = ph * (float)(2*base - 8);
    float sa, ca, s2p, c2p;
    __sincosf(a0, &sa, &ca);
    __sincosf(2.f*ph, &s2p, &c2p);
    cplx step = make_float2(c2p, s2p);
    zp[0] = make_float2(ca, sa);
    #pragma unroll
    for(int j=1;j<5;j++) zp[j] = cmul(zp[j-1], step);
  }

  // H^8 |0> with cycle-0 zphase folded into the init (saves 16 cmuls)
  cplx v[16];
  #pragma unroll
  for(int r=0;r<16;r++){
    cplx z = zp[__popc(r)];
    v[r] = make_float2(0.0625f*z.x, 0.0625f*z.y);
  }

  #pragma unroll 1
  for(int cyc=0;cyc<4;cyc++){
    if(cyc){
      #pragma unroll
      for(int r=0;r<16;r++) v[r] = cmul(v[r], zp[__popc(r)]);
    }
    // even pairs
    rxx_reg<12>(v, c, s);          // (0,1): reg bits 3,2
    rxx_reg<3>(v, c, s);           // (2,3): reg bits 1,0
    rxx_lane<SH_DPP3>(v, c, s);    // (4,5): lane mask 3
    rxx_lane<SH_SWZ12>(v, c, s);   // (6,7): lane mask 12
    // odd pairs
    rxx_reg<6>(v, c, s);           // (1,2): reg bits 2,1
    rxx_mix34(v, c, s);            // (3,4): reg bit0 + lane bit0
    rxx_lane<SH_SWZ6>(v, c, s);    // (5,6): lane mask 6
  }

  // convs (U3s folded in by setup kernel)
  conv_reg<4,8>(v, Mg +  0);                                  // (1,0)
  conv_reg<1,2>(v, Mg + 16);                                  // (3,2)
  conv_lane<SH_DPP2,SH_DPP1,SH_DPP3>(v, Mg + 32, 2*s1 + s0);  // (5,4)
  conv_lane<SH_ROR8,SH_SWZ4,SH_SWZ12>(v, Mg + 48, 2*s3 + s2); // (7,6)
  conv_reg<1,4>(v, Mg + 64);                                  // (3,1)
  conv_lane<SH_ROR8,SH_DPP2,SH_SWZ10>(v, Mg + 80, 2*s3 + s1); // (7,5)
  conv_53(v, Mg + 96, s1);                                    // (5,3)

  // <Z_3> = sign from r bit0 ; <Z_7> = sign from s bit3
  float tot = 0.f, z3 = 0.f;
  #pragma unroll
  for(int r=0;r<16;r++){
    float m = v[r].x*v[r].x + v[r].y*v[r].y;
    tot += m;
    z3 += (r & 1) ? -m : m;
  }
  float z7 = (s_ & 8) ? -tot : tot;
  // xor-reduce over the 16 lanes of this element
  z3 += xdpp<DPP_XOR1>(z3);  z7 += xdpp<DPP_XOR1>(z7);
  z3 += xdpp<DPP_XOR2>(z3);  z7 += xdpp<DPP_XOR2>(z7);
  z3 += xswz<4>(z3);         z7 += xswz<4>(z7);
  z3 += xdpp<DPP_ROR8>(z3);  z7 += xdpp<DPP_ROR8>(z7);

  // MLP tail, parallelized: lane j<10 computes neuron j, butterfly-sum
  float acc = 0.f;
  if(s_ < 10){
    float hv = tanhf(z3*w1[2*s_] + z7*w1[2*s_+1] + b1[s_]);
    acc = hv * w2[s_];
  }
  acc += xdpp<DPP_XOR1>(acc);
  acc += xdpp<DPP_XOR2>(acc);
  acc += xswz<4>(acc);
  acc += xdpp<DPP_ROR8>(acc);

  if(s_ == 0){
    float a = acc + b2[0];
    out[b] = 1.f / (1.f + __expf(-a));
  }
}

extern "C" void kernel_launch(void* const* d_in, const int* in_sizes, int n_in,
                              void* d_out, int out_size, void* d_ws, size_t ws_size,
                              hipStream_t stream) {
  const float* theta = (const float*)d_in[0];
  const float* phi   = (const float*)d_in[1];
  const float* rz    = (const float*)d_in[2];
  const float* ry    = (const float*)d_in[3];
  const float* u3    = (const float*)d_in[4];
  const float* w1    = (const float*)d_in[5];
  const float* b1    = (const float*)d_in[6];
  const float* w2    = (const float*)d_in[7];
  const float* b2    = (const float*)d_in[8];
  cplx* M = (cplx*)d_ws;   // 112 cplx = 896 B

  hipLaunchKernelGGL(setup_conv_kernel, dim3(1), dim3(32), 0, stream, rz, ry, u3, M);
  hipLaunchKernelGGL(qcnn_kernel, dim3(8192/16), dim3(256), 0, stream,
                     theta, phi, M, w1, b1, w2, b2, (float*)d_out);
}

// Round 2
// 90.901 us; speedup vs baseline: 1.0071x; 1.0071x over previous
//
#include <hip/hip_runtime.h>

typedef float2 cplx;

__device__ __forceinline__ cplx cmul(cplx a, cplx b){
  return make_float2(a.x*b.x - a.y*b.y, a.x*b.y + a.y*b.x);
}
__device__ __forceinline__ cplx cmad(cplx a, cplx b, cplx acc){  // acc + a*b
  return make_float2(acc.x + a.x*b.x - a.y*b.y, acc.y + a.x*b.y + a.y*b.x);
}

// ======================= conv-matrix setup (now fused, per-block into LDS) =======================
__device__ __forceinline__ void rz_gate(cplx* st, float t, int bmask){
  float s, c; sincosf(0.5f*t, &s, &c);
  cplx em = make_float2(c, -s), ep = make_float2(c, s);
  for(int k=0;k<4;k++) st[k] = cmul(st[k], (k & bmask) ? ep : em);
}
__device__ __forceinline__ void ry_gate_q(cplx* st, float t){
  float s, c; sincosf(0.5f*t, &s, &c);
  for(int bp=0;bp<2;bp++){
    cplx a0 = st[bp], a1 = st[2+bp];
    st[bp]   = make_float2(c*a0.x - s*a1.x, c*a0.y - s*a1.y);
    st[2+bp] = make_float2(s*a0.x + c*a1.x, s*a0.y + c*a1.y);
  }
}
__device__ __forceinline__ void u3_gate(cplx* st, const float* p, int onq){
  float th=p[0], ph=p[1], la=p[2];
  float ss,cc,sl,cl,sp,cp,spl,cpl;
  sincosf(0.5f*th,&ss,&cc); sincosf(la,&sl,&cl); sincosf(ph,&sp,&cp); sincosf(ph+la,&spl,&cpl);
  cplx u00=make_float2(cc,0.f), u01=make_float2(-cl*ss,-sl*ss);
  cplx u10=make_float2(cp*ss,sp*ss), u11=make_float2(cpl*cc,spl*cc);
  if(onq){
    for(int bp=0;bp<2;bp++){
      cplx a0=st[bp], a1=st[2+bp];
      st[bp]   = cmad(u01,a1,cmul(u00,a0));
      st[2+bp] = cmad(u11,a1,cmul(u10,a0));
    }
  } else {
    for(int bq=0;bq<2;bq++){
      cplx a0=st[2*bq], a1=st[2*bq+1];
      st[2*bq]   = cmad(u01,a1,cmul(u00,a0));
      st[2*bq+1] = cmad(u11,a1,cmul(u10,a0));
    }
  }
}

// ======================= main kernel =======================
// 16 amplitudes per lane, 16 lanes per element, 4 elements per wave.
// Amplitude i[7:0]; wire w <-> bit (7-w).
// Register index r[3:0] = i[7:4]  (wires 0,1,2,3 -> reg masks 8,4,2,1)
// Sublane s[3:0]: s0=wire4(i3), s1=wire5(i2), s2=wire6(i1), s3=wire7(i0)
//   -> lane xor masks: w4=1, w5=2, w6=4, w7=8
// DPP (VALU pipe): masks 1 (quad xor1), 2 (xor2), 3 (xor3), 8 (row_ror:8)
// ds_swizzle (LDS pipe): masks 4, 6, 10, 12

#define DPP_XOR1 0xB1   // quad_perm [1,0,3,2]
#define DPP_XOR2 0x4E   // quad_perm [2,3,0,1]
#define DPP_XOR3 0x1B   // quad_perm [3,2,1,0]
#define DPP_ROR8 0x128  // row_ror:8 == xor 8 within 16-lane row

template<int C>
__device__ __forceinline__ float xdpp(float x){
  return __builtin_bit_cast(float,
    __builtin_amdgcn_mov_dpp(__builtin_bit_cast(int, x), C, 0xF, 0xF, true));
}
template<int MASK>
__device__ __forceinline__ float xswz(float x){
  return __builtin_bit_cast(float,
    __builtin_amdgcn_ds_swizzle(__builtin_bit_cast(int, x), (MASK<<10) | 0x1F));
}

enum Sh { SH_DPP1, SH_DPP2, SH_DPP3, SH_ROR8, SH_SWZ4, SH_SWZ6, SH_SWZ10, SH_SWZ12 };

template<Sh S> __device__ __forceinline__ float shf(float x){
  if      constexpr(S==SH_DPP1)  return xdpp<DPP_XOR1>(x);
  else if constexpr(S==SH_DPP2)  return xdpp<DPP_XOR2>(x);
  else if constexpr(S==SH_DPP3)  return xdpp<DPP_XOR3>(x);
  else if constexpr(S==SH_ROR8)  return xdpp<DPP_ROR8>(x);
  else if constexpr(S==SH_SWZ4)  return xswz<4>(x);
  else if constexpr(S==SH_SWZ6)  return xswz<6>(x);
  else if constexpr(S==SH_SWZ10) return xswz<10>(x);
  else                           return xswz<12>(x);
}
template<Sh S> __device__ __forceinline__ cplx shc(cplx a){
  return make_float2(shf<S>(a.x), shf<S>(a.y));
}

// rxx: new = c*psi - i*s*partner  -> x' = c*x + s*p.y ; y' = c*y - s*p.x
template<int MR>
__device__ __forceinline__ void rxx_reg(cplx* v, float c, float s){
  #pragma unroll
  for(int r=0;r<16;r++){
    int q = r ^ MR;
    if(r > q) continue;
    cplx a = v[r], b = v[q];
    v[r] = make_float2(c*a.x + s*b.y, c*a.y - s*b.x);
    v[q] = make_float2(c*b.x + s*a.y, c*b.y - s*a.x);
  }
}
template<Sh S>
__device__ __forceinline__ void rxx_lane(cplx* v, float c, float s){
  #pragma unroll
  for(int r=0;r<16;r++){
    cplx p = shc<S>(v[r]);
    v[r] = make_float2(c*v[r].x + s*p.y, c*v[r].y - s*p.x);
  }
}
// pair (3,4): reg mask 1 + lane xor1
__device__ __forceinline__ void rxx_mix34(cplx* v, float c, float s){
  #pragma unroll
  for(int r=0;r<16;r+=2){
    cplx pa = shc<SH_DPP1>(v[r^1]);
    cplx pb = shc<SH_DPP1>(v[r]);
    cplx a = v[r], b = v[r^1];
    v[r]   = make_float2(c*a.x + s*pa.y, c*a.y - s*pa.x);
    v[r^1] = make_float2(c*b.x + s*pb.y, c*b.y - s*pb.x);
  }
}

// conv on two register wires: group {r, r^MP, r^MQ, r^MQ^MP} = columns 0..3
template<int MQ, int MP>
__device__ __forceinline__ void conv_reg(cplx* v, const cplx* M){
  #pragma unroll
  for(int r=0;r<16;r++){
    if((r & (MQ|MP)) != 0) continue;
    cplx a0=v[r], a1=v[r^MP], a2=v[r^MQ], a3=v[r^MQ^MP];
    v[r]        = cmad(M[3], a3, cmad(M[2], a2, cmad(M[1], a1, cmul(M[0], a0))));
    v[r^MP]     = cmad(M[7], a3, cmad(M[6], a2, cmad(M[5], a1, cmul(M[4], a0))));
    v[r^MQ]     = cmad(M[11],a3, cmad(M[10],a2, cmad(M[9], a1, cmul(M[8], a0))));
    v[r^MQ^MP]  = cmad(M[15],a3, cmad(M[14],a2, cmad(M[13],a1, cmul(M[12],a0))));
  }
}

// conv on two lane wires; k = 2*bit_q + bit_p (per-lane, r-independent)
template<Sh SQ, Sh SP, Sh SB>
__device__ __forceinline__ void conv_lane(cplx* v, const cplx* M, int k){
  cplx es = M[k*4 + k], ep = M[k*4 + (k^1)], eq = M[k*4 + (k^2)], eb = M[k*4 + (k^3)];
  #pragma unroll
  for(int r=0;r<16;r++){
    cplx pq = shc<SQ>(v[r]);
    cplx pp = shc<SP>(v[r]);
    cplx pb = shc<SB>(v[r]);
    v[r] = cmad(eb, pb, cmad(eq, pq, cmad(ep, pp, cmul(es, v[r]))));
  }
}

// conv (5,3): q = wire5 (lane s1, xor2 DPP), p = wire3 (reg bit 0)
__device__ __forceinline__ void conv_53(cplx* v, const cplx* M, int s1){
  int t = 2*s1, u = 2 - t;
  const cplx* r0 = M + t*4;        // row k = t   (held bp=0)
  const cplx* r1 = M + (t+1)*4;    // row k = t+1 (held bp=1)
  cplx e00=r0[t], e01=r0[t+1], e02=r0[u], e03=r0[u+1];
  cplx e10=r1[t], e11=r1[t+1], e12=r1[u], e13=r1[u+1];
  #pragma unroll
  for(int r=0;r<16;r+=2){
    cplx pv0 = shc<SH_DPP2>(v[r]);     // partner (q flipped) of bp=0
    cplx pv1 = shc<SH_DPP2>(v[r+1]);   // partner of bp=1
    cplx a0 = v[r], a1 = v[r+1];
    v[r]   = cmad(e03, pv1, cmad(e02, pv0, cmad(e01, a1, cmul(e00, a0))));
    v[r+1] = cmad(e13, pv1, cmad(e12, pv0, cmad(e11, a1, cmul(e10, a0))));
  }
}

__global__ void __launch_bounds__(256) qcnn_kernel(
    const float* __restrict__ theta, const float* __restrict__ phi,
    const float* __restrict__ rz, const float* __restrict__ ry,
    const float* __restrict__ u3,
    const float* __restrict__ w1, const float* __restrict__ b1,
    const float* __restrict__ w2, const float* __restrict__ b2,
    float* __restrict__ out){
  __shared__ cplx Msh[112];

  int tid  = threadIdx.x;

  // ---- fused setup: first 28 threads build the 7 folded conv matrices in LDS ----
  if(tid < 28){
    int ci = tid >> 2, col = tid & 3;
    const float* rz3 = rz + 3*ci;
    const float* ry2 = ry + 2*ci;
    int u3slot = 0, u3idx = 0;
    if(ci <= 3){ u3slot = 1; u3idx = ci; }
    else if(ci == 5){ u3slot = 1; u3idx = 5; }
    else if(ci == 6){ u3slot = 2; u3idx = 4; }
    cplx st[4];
    for(int k=0;k<4;k++) st[k] = make_float2(k==col ? 1.f : 0.f, 0.f);
    rz_gate(st, rz3[0], 2);
    { cplx tmp=st[2]; st[2]=st[3]; st[3]=tmp; }
    rz_gate(st, rz3[1], 1);
    ry_gate_q(st, ry2[0]);
    { cplx tmp=st[1]; st[1]=st[3]; st[3]=tmp; }
    ry_gate_q(st, ry2[1]);
    { cplx tmp=st[2]; st[2]=st[3]; st[3]=tmp; }
    rz_gate(st, rz3[2], 1);
    if(u3slot == 1)      u3_gate(st, u3+3*u3idx, 1);
    else if(u3slot == 2) u3_gate(st, u3+3*u3idx, 0);
    for(int k=0;k<4;k++) Msh[ci*16 + k*4 + col] = st[k];
  }
  __syncthreads();

  // ---- main body (unchanged, verified) ----
  int s_   = tid & 15;                       // sublane within element (DPP-row aligned)
  int b    = blockIdx.x*16 + (tid >> 4);     // element id
  int s0 = s_&1, s1 = (s_>>1)&1, s2 = (s_>>2)&1, s3 = (s_>>3)&1;

  float th = theta[b], ph = phi[b];
  float c, s;
  __sincosf(th, &s, &c);

  // zphase factors: cis(phi*(2*(popc(s)+popc(r)) - 8)), popc(r) in 0..4
  cplx zp[5];
  {
    int base = __popc(s_);
    float a0 = ph * (float)(2*base - 8);
    float sa, ca, s2p, c2p;
    __sincosf(a0, &sa, &ca);
    __sincosf(2.f*ph, &s2p, &c2p);
    cplx step = make_float2(c2p, s2p);
    zp[0] = make_float2(ca, sa);
    #pragma unroll
    for(int j=1;j<5;j++) zp[j] = cmul(zp[j-1], step);
  }

  // H^8 |0> with cycle-0 zphase folded into the init (saves 16 cmuls)
  cplx v[16];
  #pragma unroll
  for(int r=0;r<16;r++){
    cplx z = zp[__popc(r)];
    v[r] = make_float2(0.0625f*z.x, 0.0625f*z.y);
  }

  #pragma unroll 1
  for(int cyc=0;cyc<4;cyc++){
    if(cyc){
      #pragma unroll
      for(int r=0;r<16;r++) v[r] = cmul(v[r], zp[__popc(r)]);
    }
    // even pairs
    rxx_reg<12>(v, c, s);          // (0,1): reg bits 3,2
    rxx_reg<3>(v, c, s);           // (2,3): reg bits 1,0
    rxx_lane<SH_DPP3>(v, c, s);    // (4,5): lane mask 3
    rxx_lane<SH_SWZ12>(v, c, s);   // (6,7): lane mask 12
    // odd pairs
    rxx_reg<6>(v, c, s);           // (1,2): reg bits 2,1
    rxx_mix34(v, c, s);            // (3,4): reg bit0 + lane bit0
    rxx_lane<SH_SWZ6>(v, c, s);    // (5,6): lane mask 6
  }

  // convs (U3s folded in by setup)
  conv_reg<4,8>(v, Msh +  0);                                  // (1,0)
  conv_reg<1,2>(v, Msh + 16);                                  // (3,2)
  conv_lane<SH_DPP2,SH_DPP1,SH_DPP3>(v, Msh + 32, 2*s1 + s0);  // (5,4)
  conv_lane<SH_ROR8,SH_SWZ4,SH_SWZ12>(v, Msh + 48, 2*s3 + s2); // (7,6)
  conv_reg<1,4>(v, Msh + 64);                                  // (3,1)
  conv_lane<SH_ROR8,SH_DPP2,SH_SWZ10>(v, Msh + 80, 2*s3 + s1); // (7,5)
  conv_53(v, Msh + 96, s1);                                    // (5,3)

  // <Z_3> = sign from r bit0 ; <Z_7> = sign from s bit3
  float tot = 0.f, z3 = 0.f;
  #pragma unroll
  for(int r=0;r<16;r++){
    float m = v[r].x*v[r].x + v[r].y*v[r].y;
    tot += m;
    z3 += (r & 1) ? -m : m;
  }
  float z7 = (s_ & 8) ? -tot : tot;
  // xor-reduce over the 16 lanes of this element
  z3 += xdpp<DPP_XOR1>(z3);  z7 += xdpp<DPP_XOR1>(z7);
  z3 += xdpp<DPP_XOR2>(z3);  z7 += xdpp<DPP_XOR2>(z7);
  z3 += xswz<4>(z3);         z7 += xswz<4>(z7);
  z3 += xdpp<DPP_ROR8>(z3);  z7 += xdpp<DPP_ROR8>(z7);

  // MLP tail, parallelized: lane j<10 computes neuron j, butterfly-sum
  float acc = 0.f;
  if(s_ < 10){
    float hv = tanhf(z3*w1[2*s_] + z7*w1[2*s_+1] + b1[s_]);
    acc = hv * w2[s_];
  }
  acc += xdpp<DPP_XOR1>(acc);
  acc += xdpp<DPP_XOR2>(acc);
  acc += xswz<4>(acc);
  acc += xdpp<DPP_ROR8>(acc);

  if(s_ == 0){
    float a = acc + b2[0];
    out[b] = 1.f / (1.f + __expf(-a));
  }
}

extern "C" void kernel_launch(void* const* d_in, const int* in_sizes, int n_in,
                              void* d_out, int out_size, void* d_ws, size_t ws_size,
                              hipStream_t stream) {
  const float* theta = (const float*)d_in[0];
  const float* phi   = (const float*)d_in[1];
  const float* rz    = (const float*)d_in[2];
  const float* ry    = (const float*)d_in[3];
  const float* u3    = (const float*)d_in[4];
  const float* w1    = (const float*)d_in[5];
  const float* b1    = (const float*)d_in[6];
  const float* w2    = (const float*)d_in[7];
  const float* b2    = (const float*)d_in[8];

  hipLaunchKernelGGL(qcnn_kernel, dim3(8192/16), dim3(256), 0, stream,
                     theta, phi, rz, ry, u3, w1, b1, w2, b2, (float*)d_out);
}

// Round 3
// 90.071 us; speedup vs baseline: 1.0164x; 1.0092x over previous
//
#include <hip/hip_runtime.h>

// packed complex: lane0 = re, lane1 = im -> v_pk_* f32 ops on gfx950
typedef float f32x2 __attribute__((ext_vector_type(2)));
typedef f32x2 cplx;

__device__ __forceinline__ cplx imul(cplx b){        // i*b = (-im, re)
  cplx r = { -b[1], b[0] }; return r;
}
__device__ __forceinline__ cplx cmul(cplx a, cplx b){
  return a.xx*b + a.yy*imul(b);
}
__device__ __forceinline__ cplx cmad(cplx a, cplx b, cplx acc){  // acc + a*b
  return acc + a.xx*b + a.yy*imul(b);
}
// rxx update: c*a - i*s*p  = (c*a0 + s*p1, c*a1 - s*p0)
__device__ __forceinline__ cplx rxx_upd(float c, cplx a, float s, cplx p){
  return c*a - s*imul(p);
}

// ======================= conv-matrix setup (fused, per-block into LDS) =======================
__device__ __forceinline__ void rz_gate(cplx* st, float t, int bmask){
  float s, c; sincosf(0.5f*t, &s, &c);
  cplx em = {c, -s}, ep = {c, s};
  for(int k=0;k<4;k++) st[k] = cmul(st[k], (k & bmask) ? ep : em);
}
__device__ __forceinline__ void ry_gate_q(cplx* st, float t){
  float s, c; sincosf(0.5f*t, &s, &c);
  for(int bp=0;bp<2;bp++){
    cplx a0 = st[bp], a1 = st[2+bp];
    st[bp]   = c*a0 - s*a1;
    st[2+bp] = s*a0 + c*a1;
  }
}
__device__ __forceinline__ void u3_gate(cplx* st, const float* p, int onq){
  float th=p[0], ph=p[1], la=p[2];
  float ss,cc,sl,cl,sp,cp,spl,cpl;
  sincosf(0.5f*th,&ss,&cc); sincosf(la,&sl,&cl); sincosf(ph,&sp,&cp); sincosf(ph+la,&spl,&cpl);
  cplx u00={cc,0.f},      u01={-cl*ss,-sl*ss};
  cplx u10={cp*ss,sp*ss}, u11={cpl*cc,spl*cc};
  if(onq){
    for(int bp=0;bp<2;bp++){
      cplx a0=st[bp], a1=st[2+bp];
      st[bp]   = cmad(u01,a1,cmul(u00,a0));
      st[2+bp] = cmad(u11,a1,cmul(u10,a0));
    }
  } else {
    for(int bq=0;bq<2;bq++){
      cplx a0=st[2*bq], a1=st[2*bq+1];
      st[2*bq]   = cmad(u01,a1,cmul(u00,a0));
      st[2*bq+1] = cmad(u11,a1,cmul(u10,a0));
    }
  }
}

// ======================= main kernel =======================
// 16 amplitudes per lane, 16 lanes per element, 4 elements per wave.
// Amplitude i[7:0]; wire w <-> bit (7-w).
// Register index r[3:0] = i[7:4]  (wires 0,1,2,3 -> reg masks 8,4,2,1)
// Sublane s[3:0]: s0=wire4, s1=wire5, s2=wire6, s3=wire7
//   -> lane xor masks: w4=1, w5=2, w6=4, w7=8
// ALL lane shuffles are now DPP (VALU pipe) — no LDS pipe:
//   xor1/2/3: quad_perm; xor8: row_ror:8
//   xor4 = half_mirror(xor7) ∘ xor3 ; xor6 = half_mirror ∘ xor1
//   xor10 = ror8 ∘ xor2            ; xor12 = mirror(xor15) ∘ xor3

#define DPP_XOR1 0xB1    // quad_perm [1,0,3,2]
#define DPP_XOR2 0x4E    // quad_perm [2,3,0,1]
#define DPP_XOR3 0x1B    // quad_perm [3,2,1,0]
#define DPP_ROR8 0x128   // row_ror:8  == xor 8 within 16-lane row
#define DPP_MIRR 0x140   // row_mirror == xor 15
#define DPP_HALF 0x141   // row_half_mirror == xor 7

template<int C>
__device__ __forceinline__ float xdpp(float x){
  return __builtin_bit_cast(float,
    __builtin_amdgcn_mov_dpp(__builtin_bit_cast(int, x), C, 0xF, 0xF, true));
}

enum Sh { SH_DPP1, SH_DPP2, SH_DPP3, SH_ROR8, SH_SWZ4, SH_SWZ6, SH_SWZ10, SH_SWZ12 };

template<Sh S> __device__ __forceinline__ float shf(float x){
  if      constexpr(S==SH_DPP1)  return xdpp<DPP_XOR1>(x);
  else if constexpr(S==SH_DPP2)  return xdpp<DPP_XOR2>(x);
  else if constexpr(S==SH_DPP3)  return xdpp<DPP_XOR3>(x);
  else if constexpr(S==SH_ROR8)  return xdpp<DPP_ROR8>(x);
  else if constexpr(S==SH_SWZ4)  return xdpp<DPP_HALF>(xdpp<DPP_XOR3>(x));   // xor7∘xor3 = xor4
  else if constexpr(S==SH_SWZ6)  return xdpp<DPP_HALF>(xdpp<DPP_XOR1>(x));   // xor7∘xor1 = xor6
  else if constexpr(S==SH_SWZ10) return xdpp<DPP_ROR8>(xdpp<DPP_XOR2>(x));   // xor8∘xor2 = xor10
  else                           return xdpp<DPP_MIRR>(xdpp<DPP_XOR3>(x));   // xor15∘xor3 = xor12
}
template<Sh S> __device__ __forceinline__ cplx shc(cplx a){
  cplx r; r[0] = shf<S>(a[0]); r[1] = shf<S>(a[1]); return r;
}

// rxx on two register wires
template<int MR>
__device__ __forceinline__ void rxx_reg(cplx* v, float c, float s){
  #pragma unroll
  for(int r=0;r<16;r++){
    int q = r ^ MR;
    if(r > q) continue;
    cplx a = v[r], b = v[q];
    v[r] = rxx_upd(c, a, s, b);
    v[q] = rxx_upd(c, b, s, a);
  }
}
template<Sh S>
__device__ __forceinline__ void rxx_lane(cplx* v, float c, float s){
  #pragma unroll
  for(int r=0;r<16;r++){
    cplx p = shc<S>(v[r]);
    v[r] = rxx_upd(c, v[r], s, p);
  }
}
// pair (3,4): reg mask 1 + lane xor1
__device__ __forceinline__ void rxx_mix34(cplx* v, float c, float s){
  #pragma unroll
  for(int r=0;r<16;r+=2){
    cplx pa = shc<SH_DPP1>(v[r^1]);
    cplx pb = shc<SH_DPP1>(v[r]);
    cplx a = v[r], b = v[r^1];
    v[r]   = rxx_upd(c, a, s, pa);
    v[r^1] = rxx_upd(c, b, s, pb);
  }
}

// conv on two register wires: group {r, r^MP, r^MQ, r^MQ^MP} = columns 0..3
template<int MQ, int MP>
__device__ __forceinline__ void conv_reg(cplx* v, const cplx* M){
  #pragma unroll
  for(int r=0;r<16;r++){
    if((r & (MQ|MP)) != 0) continue;
    cplx a0=v[r], a1=v[r^MP], a2=v[r^MQ], a3=v[r^MQ^MP];
    v[r]        = cmad(M[3], a3, cmad(M[2], a2, cmad(M[1], a1, cmul(M[0], a0))));
    v[r^MP]     = cmad(M[7], a3, cmad(M[6], a2, cmad(M[5], a1, cmul(M[4], a0))));
    v[r^MQ]     = cmad(M[11],a3, cmad(M[10],a2, cmad(M[9], a1, cmul(M[8], a0))));
    v[r^MQ^MP]  = cmad(M[15],a3, cmad(M[14],a2, cmad(M[13],a1, cmul(M[12],a0))));
  }
}

// conv on two lane wires; k = 2*bit_q + bit_p (per-lane, r-independent)
template<Sh SQ, Sh SP, Sh SB>
__device__ __forceinline__ void conv_lane(cplx* v, const cplx* M, int k){
  cplx es = M[k*4 + k], ep = M[k*4 + (k^1)], eq = M[k*4 + (k^2)], eb = M[k*4 + (k^3)];
  #pragma unroll
  for(int r=0;r<16;r++){
    cplx pq = shc<SQ>(v[r]);
    cplx pp = shc<SP>(v[r]);
    cplx pb = shc<SB>(v[r]);
    v[r] = cmad(eb, pb, cmad(eq, pq, cmad(ep, pp, cmul(es, v[r]))));
  }
}

// conv (5,3): q = wire5 (lane s1, xor2 DPP), p = wire3 (reg bit 0)
__device__ __forceinline__ void conv_53(cplx* v, const cplx* M, int s1){
  int t = 2*s1, u = 2 - t;
  const cplx* r0 = M + t*4;        // row k = t   (held bp=0)
  const cplx* r1 = M + (t+1)*4;    // row k = t+1 (held bp=1)
  cplx e00=r0[t], e01=r0[t+1], e02=r0[u], e03=r0[u+1];
  cplx e10=r1[t], e11=r1[t+1], e12=r1[u], e13=r1[u+1];
  #pragma unroll
  for(int r=0;r<16;r+=2){
    cplx pv0 = shc<SH_DPP2>(v[r]);     // partner (q flipped) of bp=0
    cplx pv1 = shc<SH_DPP2>(v[r+1]);   // partner of bp=1
    cplx a0 = v[r], a1 = v[r+1];
    v[r]   = cmad(e03, pv1, cmad(e02, pv0, cmad(e01, a1, cmul(e00, a0))));
    v[r+1] = cmad(e13, pv1, cmad(e12, pv0, cmad(e11, a1, cmul(e10, a0))));
  }
}

__global__ void __launch_bounds__(256) qcnn_kernel(
    const float* __restrict__ theta, const float* __restrict__ phi,
    const float* __restrict__ rz, const float* __restrict__ ry,
    const float* __restrict__ u3,
    const float* __restrict__ w1, const float* __restrict__ b1,
    const float* __restrict__ w2, const float* __restrict__ b2,
    float* __restrict__ out){
  __shared__ cplx Msh[112];

  int tid  = threadIdx.x;

  // ---- fused setup: first 28 threads build the 7 folded conv matrices in LDS ----
  if(tid < 28){
    int ci = tid >> 2, col = tid & 3;
    const float* rz3 = rz + 3*ci;
    const float* ry2 = ry + 2*ci;
    int u3slot = 0, u3idx = 0;
    if(ci <= 3){ u3slot = 1; u3idx = ci; }
    else if(ci == 5){ u3slot = 1; u3idx = 5; }
    else if(ci == 6){ u3slot = 2; u3idx = 4; }
    cplx st[4];
    for(int k=0;k<4;k++){ cplx z = {k==col ? 1.f : 0.f, 0.f}; st[k] = z; }
    rz_gate(st, rz3[0], 2);
    { cplx tmp=st[2]; st[2]=st[3]; st[3]=tmp; }
    rz_gate(st, rz3[1], 1);
    ry_gate_q(st, ry2[0]);
    { cplx tmp=st[1]; st[1]=st[3]; st[3]=tmp; }
    ry_gate_q(st, ry2[1]);
    { cplx tmp=st[2]; st[2]=st[3]; st[3]=tmp; }
    rz_gate(st, rz3[2], 1);
    if(u3slot == 1)      u3_gate(st, u3+3*u3idx, 1);
    else if(u3slot == 2) u3_gate(st, u3+3*u3idx, 0);
    for(int k=0;k<4;k++) Msh[ci*16 + k*4 + col] = st[k];
  }
  __syncthreads();

  // ---- main body ----
  int s_   = tid & 15;                       // sublane within element (DPP-row aligned)
  int b    = blockIdx.x*16 + (tid >> 4);     // element id
  int s0 = s_&1, s1 = (s_>>1)&1, s2 = (s_>>2)&1, s3 = (s_>>3)&1;
  (void)s2;

  float th = theta[b], ph = phi[b];
  float c, s;
  __sincosf(th, &s, &c);

  // zphase factors: cis(phi*(2*(popc(s)+popc(r)) - 8)), popc(r) in 0..4
  cplx zp[5];
  {
    int base = __popc(s_);
    float a0 = ph * (float)(2*base - 8);
    float sa, ca, s2p, c2p;
    __sincosf(a0, &sa, &ca);
    __sincosf(2.f*ph, &s2p, &c2p);
    cplx step = {c2p, s2p};
    cplx z0 = {ca, sa};
    zp[0] = z0;
    #pragma unroll
    for(int j=1;j<5;j++) zp[j] = cmul(zp[j-1], step);
  }

  // H^8 |0> with cycle-0 zphase folded into the init
  cplx v[16];
  #pragma unroll
  for(int r=0;r<16;r++) v[r] = 0.0625f * zp[__popc(r)];

  #pragma unroll 1
  for(int cyc=0;cyc<4;cyc++){
    if(cyc){
      #pragma unroll
      for(int r=0;r<16;r++) v[r] = cmul(v[r], zp[__popc(r)]);
    }
    // even pairs
    rxx_reg<12>(v, c, s);          // (0,1): reg bits 3,2
    rxx_reg<3>(v, c, s);           // (2,3): reg bits 1,0
    rxx_lane<SH_DPP3>(v, c, s);    // (4,5): lane mask 3
    rxx_lane<SH_SWZ12>(v, c, s);   // (6,7): lane mask 12
    // odd pairs
    rxx_reg<6>(v, c, s);           // (1,2): reg bits 2,1
    rxx_mix34(v, c, s);            // (3,4): reg bit0 + lane bit0
    rxx_lane<SH_SWZ6>(v, c, s);    // (5,6): lane mask 6
  }

  // convs (U3s folded in by setup)
  conv_reg<4,8>(v, Msh +  0);                                  // (1,0)
  conv_reg<1,2>(v, Msh + 16);                                  // (3,2)
  conv_lane<SH_DPP2,SH_DPP1,SH_DPP3>(v, Msh + 32, 2*s1 + s0);  // (5,4)
  conv_lane<SH_ROR8,SH_SWZ4,SH_SWZ12>(v, Msh + 48, 2*s3 + s2); // (7,6)
  conv_reg<1,4>(v, Msh + 64);                                  // (3,1)
  conv_lane<SH_ROR8,SH_DPP2,SH_SWZ10>(v, Msh + 80, 2*s3 + s1); // (7,5)
  conv_53(v, Msh + 96, s1);                                    // (5,3)

  // <Z_3> = sign from r bit0 ; <Z_7> = sign from s bit3
  float tot = 0.f, z3 = 0.f;
  #pragma unroll
  for(int r=0;r<16;r++){
    f32x2 q = v[r]*v[r];
    float m = q[0] + q[1];
    tot += m;
    z3 += (r & 1) ? -m : m;
  }
  float z7 = (s_ & 8) ? -tot : tot;
  // xor-reduce over the 16 lanes: masks {1,2,7,8} generate the full group
  z3 += xdpp<DPP_XOR1>(z3);  z7 += xdpp<DPP_XOR1>(z7);
  z3 += xdpp<DPP_XOR2>(z3);  z7 += xdpp<DPP_XOR2>(z7);
  z3 += xdpp<DPP_HALF>(z3);  z7 += xdpp<DPP_HALF>(z7);
  z3 += xdpp<DPP_ROR8>(z3);  z7 += xdpp<DPP_ROR8>(z7);

  // MLP tail, parallelized: lane j<10 computes neuron j, butterfly-sum
  float acc = 0.f;
  if(s_ < 10){
    float hv = tanhf(z3*w1[2*s_] + z7*w1[2*s_+1] + b1[s_]);
    acc = hv * w2[s_];
  }
  acc += xdpp<DPP_XOR1>(acc);
  acc += xdpp<DPP_XOR2>(acc);
  acc += xdpp<DPP_HALF>(acc);
  acc += xdpp<DPP_ROR8>(acc);

  if(s_ == 0){
    float a = acc + b2[0];
    out[b] = 1.f / (1.f + __expf(-a));
  }
}

extern "C" void kernel_launch(void* const* d_in, const int* in_sizes, int n_in,
                              void* d_out, int out_size, void* d_ws, size_t ws_size,
                              hipStream_t stream) {
  const float* theta = (const float*)d_in[0];
  const float* phi   = (const float*)d_in[1];
  const float* rz    = (const float*)d_in[2];
  const float* ry    = (const float*)d_in[3];
  const float* u3    = (const float*)d_in[4];
  const float* w1    = (const float*)d_in[5];
  const float* b1    = (const float*)d_in[6];
  const float* w2    = (const float*)d_in[7];
  const float* b2    = (const float*)d_in[8];

  hipLaunchKernelGGL(qcnn_kernel, dim3(8192/16), dim3(256), 0, stream,
                     theta, phi, rz, ry, u3, w1, b1, w2, b2, (float*)d_out);
}

// Round 4
// 85.046 us; speedup vs baseline: 1.0765x; 1.0591x over previous
//
#include <hip/hip_runtime.h>

// packed complex: lo = re, hi = im. All complex arithmetic forced to
// v_pk_mul_f32 / v_pk_fma_f32 (VOP3P) via inline asm with op_sel/neg
// modifiers: 2 instructions per complex mul/mad instead of 4 scalar.
typedef float f32x2 __attribute__((ext_vector_type(2)));
typedef f32x2 cplx;

// t = (a.lo*b.lo, a.lo*b.hi)   -- broadcast a.lo
__device__ __forceinline__ cplx pk_bcastlo_mul(cplx a, cplx b){
  cplx t;
  asm("v_pk_mul_f32 %0, %1, %2 op_sel:[0,0] op_sel_hi:[0,1]"
      : "=v"(t) : "v"(a), "v"(b));
  return t;
}
// d = (t.lo - a.hi*b.hi, t.hi + a.hi*b.lo)   -- the "i*" cross term
__device__ __forceinline__ cplx pk_cross_mad(cplx a, cplx b, cplx t){
  cplx d;
  asm("v_pk_fma_f32 %0, %1, %2, %3 op_sel:[1,1,0] op_sel_hi:[1,0,1] neg_lo:[0,1,0]"
      : "=v"(d) : "v"(a), "v"(b), "v"(t));
  return d;
}
// t = (a.lo*b.lo + acc.lo, a.lo*b.hi + acc.hi)
__device__ __forceinline__ cplx pk_bcastlo_mad(cplx a, cplx b, cplx acc){
  cplx t;
  asm("v_pk_fma_f32 %0, %1, %2, %3 op_sel:[0,0,0] op_sel_hi:[0,1,1]"
      : "=v"(t) : "v"(a), "v"(b), "v"(acc));
  return t;
}
// d = (t.lo + cs.hi*p.hi, t.hi - cs.hi*p.lo)   -- rxx cross term (-i*s*p)
__device__ __forceinline__ cplx pk_rxx_cross(cplx cs, cplx p, cplx t){
  cplx d;
  asm("v_pk_fma_f32 %0, %1, %2, %3 op_sel:[1,1,0] op_sel_hi:[1,0,1] neg_hi:[0,1,0]"
      : "=v"(d) : "v"(cs), "v"(p), "v"(t));
  return d;
}

__device__ __forceinline__ cplx cmul(cplx a, cplx b){
  return pk_cross_mad(a, b, pk_bcastlo_mul(a, b));
}
__device__ __forceinline__ cplx cmad(cplx a, cplx b, cplx acc){  // acc + a*b
  return pk_cross_mad(a, b, pk_bcastlo_mad(a, b, acc));
}
// rxx update: c*a - i*s*p, cs = (c, s)
__device__ __forceinline__ cplx rxx_upd(cplx cs, cplx a, cplx p){
  return pk_rxx_cross(cs, p, pk_bcastlo_mul(cs, a));
}

// ======================= conv-matrix setup (fused, per-block into LDS) =======================
__device__ __forceinline__ void rz_gate(cplx* st, float t, int bmask){
  float s, c; sincosf(0.5f*t, &s, &c);
  cplx em = {c, -s}, ep = {c, s};
  for(int k=0;k<4;k++) st[k] = cmul(st[k], (k & bmask) ? ep : em);
}
__device__ __forceinline__ void ry_gate_q(cplx* st, float t){
  float s, c; sincosf(0.5f*t, &s, &c);
  for(int bp=0;bp<2;bp++){
    cplx a0 = st[bp], a1 = st[2+bp];
    st[bp]   = c*a0 - s*a1;
    st[2+bp] = s*a0 + c*a1;
  }
}
__device__ __forceinline__ void u3_gate(cplx* st, const float* p, int onq){
  float th=p[0], ph=p[1], la=p[2];
  float ss,cc,sl,cl,sp,cp,spl,cpl;
  sincosf(0.5f*th,&ss,&cc); sincosf(la,&sl,&cl); sincosf(ph,&sp,&cp); sincosf(ph+la,&spl,&cpl);
  cplx u00={cc,0.f},      u01={-cl*ss,-sl*ss};
  cplx u10={cp*ss,sp*ss}, u11={cpl*cc,spl*cc};
  if(onq){
    for(int bp=0;bp<2;bp++){
      cplx a0=st[bp], a1=st[2+bp];
      st[bp]   = cmad(u01,a1,cmul(u00,a0));
      st[2+bp] = cmad(u11,a1,cmul(u10,a0));
    }
  } else {
    for(int bq=0;bq<2;bq++){
      cplx a0=st[2*bq], a1=st[2*bq+1];
      st[2*bq]   = cmad(u01,a1,cmul(u00,a0));
      st[2*bq+1] = cmad(u11,a1,cmul(u10,a0));
    }
  }
}

// ======================= main kernel =======================
// 16 amplitudes per lane, 16 lanes per element, 4 elements per wave.
// Amplitude i[7:0]; wire w <-> bit (7-w).
// Register index r[3:0] = i[7:4]  (wires 0,1,2,3 -> reg masks 8,4,2,1)
// Sublane s[3:0]: s0=wire4, s1=wire5, s2=wire6, s3=wire7
//   -> lane xor masks: w4=1, w5=2, w6=4, w7=8
// ALL lane shuffles are DPP (VALU pipe) — no LDS pipe:
//   xor1/2/3: quad_perm; xor8: row_ror:8
//   xor4 = half_mirror(xor7) ∘ xor3 ; xor6 = half_mirror ∘ xor1
//   xor10 = ror8 ∘ xor2            ; xor12 = mirror(xor15) ∘ xor3

#define DPP_XOR1 0xB1    // quad_perm [1,0,3,2]
#define DPP_XOR2 0x4E    // quad_perm [2,3,0,1]
#define DPP_XOR3 0x1B    // quad_perm [3,2,1,0]
#define DPP_ROR8 0x128   // row_ror:8  == xor 8 within 16-lane row
#define DPP_MIRR 0x140   // row_mirror == xor 15
#define DPP_HALF 0x141   // row_half_mirror == xor 7

template<int C>
__device__ __forceinline__ float xdpp(float x){
  return __builtin_bit_cast(float,
    __builtin_amdgcn_mov_dpp(__builtin_bit_cast(int, x), C, 0xF, 0xF, true));
}

enum Sh { SH_DPP1, SH_DPP2, SH_DPP3, SH_ROR8, SH_SWZ4, SH_SWZ6, SH_SWZ10, SH_SWZ12 };

template<Sh S> __device__ __forceinline__ float shf(float x){
  if      constexpr(S==SH_DPP1)  return xdpp<DPP_XOR1>(x);
  else if constexpr(S==SH_DPP2)  return xdpp<DPP_XOR2>(x);
  else if constexpr(S==SH_DPP3)  return xdpp<DPP_XOR3>(x);
  else if constexpr(S==SH_ROR8)  return xdpp<DPP_ROR8>(x);
  else if constexpr(S==SH_SWZ4)  return xdpp<DPP_HALF>(xdpp<DPP_XOR3>(x));   // xor7∘xor3 = xor4
  else if constexpr(S==SH_SWZ6)  return xdpp<DPP_HALF>(xdpp<DPP_XOR1>(x));   // xor7∘xor1 = xor6
  else if constexpr(S==SH_SWZ10) return xdpp<DPP_ROR8>(xdpp<DPP_XOR2>(x));   // xor8∘xor2 = xor10
  else                           return xdpp<DPP_MIRR>(xdpp<DPP_XOR3>(x));   // xor15∘xor3 = xor12
}
template<Sh S> __device__ __forceinline__ cplx shc(cplx a){
  cplx r; r[0] = shf<S>(a[0]); r[1] = shf<S>(a[1]); return r;
}

// rxx on two register wires
template<int MR>
__device__ __forceinline__ void rxx_reg(cplx* v, cplx cs){
  #pragma unroll
  for(int r=0;r<16;r++){
    int q = r ^ MR;
    if(r > q) continue;
    cplx a = v[r], b = v[q];
    v[r] = rxx_upd(cs, a, b);
    v[q] = rxx_upd(cs, b, a);
  }
}
template<Sh S>
__device__ __forceinline__ void rxx_lane(cplx* v, cplx cs){
  #pragma unroll
  for(int r=0;r<16;r++){
    cplx p = shc<S>(v[r]);
    v[r] = rxx_upd(cs, v[r], p);
  }
}
// pair (3,4): reg mask 1 + lane xor1
__device__ __forceinline__ void rxx_mix34(cplx* v, cplx cs){
  #pragma unroll
  for(int r=0;r<16;r+=2){
    cplx pa = shc<SH_DPP1>(v[r^1]);
    cplx pb = shc<SH_DPP1>(v[r]);
    cplx a = v[r], b = v[r^1];
    v[r]   = rxx_upd(cs, a, pa);
    v[r^1] = rxx_upd(cs, b, pb);
  }
}

// conv on two register wires: group {r, r^MP, r^MQ, r^MQ^MP} = columns 0..3
template<int MQ, int MP>
__device__ __forceinline__ void conv_reg(cplx* v, const cplx* M){
  #pragma unroll
  for(int r=0;r<16;r++){
    if((r & (MQ|MP)) != 0) continue;
    cplx a0=v[r], a1=v[r^MP], a2=v[r^MQ], a3=v[r^MQ^MP];
    v[r]        = cmad(M[3], a3, cmad(M[2], a2, cmad(M[1], a1, cmul(M[0], a0))));
    v[r^MP]     = cmad(M[7], a3, cmad(M[6], a2, cmad(M[5], a1, cmul(M[4], a0))));
    v[r^MQ]     = cmad(M[11],a3, cmad(M[10],a2, cmad(M[9], a1, cmul(M[8], a0))));
    v[r^MQ^MP]  = cmad(M[15],a3, cmad(M[14],a2, cmad(M[13],a1, cmul(M[12],a0))));
  }
}

// conv on two lane wires; k = 2*bit_q + bit_p (per-lane, r-independent)
template<Sh SQ, Sh SP, Sh SB>
__device__ __forceinline__ void conv_lane(cplx* v, const cplx* M, int k){
  cplx es = M[k*4 + k], ep = M[k*4 + (k^1)], eq = M[k*4 + (k^2)], eb = M[k*4 + (k^3)];
  #pragma unroll
  for(int r=0;r<16;r++){
    cplx pq = shc<SQ>(v[r]);
    cplx pp = shc<SP>(v[r]);
    cplx pb = shc<SB>(v[r]);
    v[r] = cmad(eb, pb, cmad(eq, pq, cmad(ep, pp, cmul(es, v[r]))));
  }
}

// conv (5,3): q = wire5 (lane s1, xor2 DPP), p = wire3 (reg bit 0)
__device__ __forceinline__ void conv_53(cplx* v, const cplx* M, int s1){
  int t = 2*s1, u = 2 - t;
  const cplx* r0 = M + t*4;        // row k = t   (held bp=0)
  const cplx* r1 = M + (t+1)*4;    // row k = t+1 (held bp=1)
  cplx e00=r0[t], e01=r0[t+1], e02=r0[u], e03=r0[u+1];
  cplx e10=r1[t], e11=r1[t+1], e12=r1[u], e13=r1[u+1];
  #pragma unroll
  for(int r=0;r<16;r+=2){
    cplx pv0 = shc<SH_DPP2>(v[r]);     // partner (q flipped) of bp=0
    cplx pv1 = shc<SH_DPP2>(v[r+1]);   // partner of bp=1
    cplx a0 = v[r], a1 = v[r+1];
    v[r]   = cmad(e03, pv1, cmad(e02, pv0, cmad(e01, a1, cmul(e00, a0))));
    v[r+1] = cmad(e13, pv1, cmad(e12, pv0, cmad(e11, a1, cmul(e10, a0))));
  }
}

__global__ void __launch_bounds__(256) qcnn_kernel(
    const float* __restrict__ theta, const float* __restrict__ phi,
    const float* __restrict__ rz, const float* __restrict__ ry,
    const float* __restrict__ u3,
    const float* __restrict__ w1, const float* __restrict__ b1,
    const float* __restrict__ w2, const float* __restrict__ b2,
    float* __restrict__ out){
  __shared__ cplx Msh[112];

  int tid  = threadIdx.x;

  // ---- fused setup: first 28 threads build the 7 folded conv matrices in LDS ----
  if(tid < 28){
    int ci = tid >> 2, col = tid & 3;
    const float* rz3 = rz + 3*ci;
    const float* ry2 = ry + 2*ci;
    int u3slot = 0, u3idx = 0;
    if(ci <= 3){ u3slot = 1; u3idx = ci; }
    else if(ci == 5){ u3slot = 1; u3idx = 5; }
    else if(ci == 6){ u3slot = 2; u3idx = 4; }
    cplx st[4];
    for(int k=0;k<4;k++){ cplx z = {k==col ? 1.f : 0.f, 0.f}; st[k] = z; }
    rz_gate(st, rz3[0], 2);
    { cplx tmp=st[2]; st[2]=st[3]; st[3]=tmp; }
    rz_gate(st, rz3[1], 1);
    ry_gate_q(st, ry2[0]);
    { cplx tmp=st[1]; st[1]=st[3]; st[3]=tmp; }
    ry_gate_q(st, ry2[1]);
    { cplx tmp=st[2]; st[2]=st[3]; st[3]=tmp; }
    rz_gate(st, rz3[2], 1);
    if(u3slot == 1)      u3_gate(st, u3+3*u3idx, 1);
    else if(u3slot == 2) u3_gate(st, u3+3*u3idx, 0);
    for(int k=0;k<4;k++) Msh[ci*16 + k*4 + col] = st[k];
  }
  __syncthreads();

  // ---- main body ----
  int s_   = tid & 15;                       // sublane within element (DPP-row aligned)
  int b    = blockIdx.x*16 + (tid >> 4);     // element id
  int s0 = s_&1, s1 = (s_>>1)&1, s2 = (s_>>2)&1, s3 = (s_>>3)&1;
  (void)s2;

  float th = theta[b], ph = phi[b];
  float c, s;
  __sincosf(th, &s, &c);
  cplx cs = {c, s};

  // zphase factors: cis(phi*(2*(popc(s)+popc(r)) - 8)), popc(r) in 0..4
  cplx zp[5];
  {
    int base = __popc(s_);
    float a0 = ph * (float)(2*base - 8);
    float sa, ca, s2p, c2p;
    __sincosf(a0, &sa, &ca);
    __sincosf(2.f*ph, &s2p, &c2p);
    cplx step = {c2p, s2p};
    cplx z0 = {ca, sa};
    zp[0] = z0;
    #pragma unroll
    for(int j=1;j<5;j++) zp[j] = cmul(zp[j-1], step);
  }

  // H^8 |0> with cycle-0 zphase folded into the init
  cplx v[16];
  #pragma unroll
  for(int r=0;r<16;r++) v[r] = 0.0625f * zp[__popc(r)];

  #pragma unroll 1
  for(int cyc=0;cyc<4;cyc++){
    if(cyc){
      #pragma unroll
      for(int r=0;r<16;r++) v[r] = cmul(v[r], zp[__popc(r)]);
    }
    // even pairs
    rxx_reg<12>(v, cs);          // (0,1): reg bits 3,2
    rxx_reg<3>(v, cs);           // (2,3): reg bits 1,0
    rxx_lane<SH_DPP3>(v, cs);    // (4,5): lane mask 3
    rxx_lane<SH_SWZ12>(v, cs);   // (6,7): lane mask 12
    // odd pairs
    rxx_reg<6>(v, cs);           // (1,2): reg bits 2,1
    rxx_mix34(v, cs);            // (3,4): reg bit0 + lane bit0
    rxx_lane<SH_SWZ6>(v, cs);    // (5,6): lane mask 6
  }

  // convs (U3s folded in by setup)
  conv_reg<4,8>(v, Msh +  0);                                  // (1,0)
  conv_reg<1,2>(v, Msh + 16);                                  // (3,2)
  conv_lane<SH_DPP2,SH_DPP1,SH_DPP3>(v, Msh + 32, 2*s1 + s0);  // (5,4)
  conv_lane<SH_ROR8,SH_SWZ4,SH_SWZ12>(v, Msh + 48, 2*s3 + s2); // (7,6)
  conv_reg<1,4>(v, Msh + 64);                                  // (3,1)
  conv_lane<SH_ROR8,SH_DPP2,SH_SWZ10>(v, Msh + 80, 2*s3 + s1); // (7,5)
  conv_53(v, Msh + 96, s1);                                    // (5,3)

  // <Z_3> = sign from r bit0 ; <Z_7> = sign from s bit3
  float tot = 0.f, z3 = 0.f;
  #pragma unroll
  for(int r=0;r<16;r++){
    float m = fmaf(v[r][0], v[r][0], v[r][1]*v[r][1]);
    tot += m;
    z3 += (r & 1) ? -m : m;
  }
  float z7 = (s_ & 8) ? -tot : tot;
  // xor-reduce over the 16 lanes: masks {1,2,7,8} generate the full group
  z3 += xdpp<DPP_XOR1>(z3);  z7 += xdpp<DPP_XOR1>(z7);
  z3 += xdpp<DPP_XOR2>(z3);  z7 += xdpp<DPP_XOR2>(z7);
  z3 += xdpp<DPP_HALF>(z3);  z7 += xdpp<DPP_HALF>(z7);
  z3 += xdpp<DPP_ROR8>(z3);  z7 += xdpp<DPP_ROR8>(z7);

  // MLP tail, parallelized: lane j<10 computes neuron j, butterfly-sum
  float acc = 0.f;
  if(s_ < 10){
    float hv = tanhf(z3*w1[2*s_] + z7*w1[2*s_+1] + b1[s_]);
    acc = hv * w2[s_];
  }
  acc += xdpp<DPP_XOR1>(acc);
  acc += xdpp<DPP_XOR2>(acc);
  acc += xdpp<DPP_HALF>(acc);
  acc += xdpp<DPP_ROR8>(acc);

  if(s_ == 0){
    float a = acc + b2[0];
    out[b] = 1.f / (1.f + __expf(-a));
  }
}

extern "C" void kernel_launch(void* const* d_in, const int* in_sizes, int n_in,
                              void* d_out, int out_size, void* d_ws, size_t ws_size,
                              hipStream_t stream) {
  const float* theta = (const float*)d_in[0];
  const float* phi   = (const float*)d_in[1];
  const float* rz    = (const float*)d_in[2];
  const float* ry    = (const float*)d_in[3];
  const float* u3    = (const float*)d_in[4];
  const float* w1    = (const float*)d_in[5];
  const float* b1    = (const float*)d_in[6];
  const float* w2    = (const float*)d_in[7];
  const float* b2    = (const float*)d_in[8];

  hipLaunchKernelGGL(qcnn_kernel, dim3(8192/16), dim3(256), 0, stream,
                     theta, phi, rz, ry, u3, w1, b1, w2, b2, (float*)d_out);
}

// Round 5
// 84.681 us; speedup vs baseline: 1.0811x; 1.0043x over previous
//
#include <hip/hip_runtime.h>

// packed complex: lo = re, hi = im. All complex arithmetic forced to
// v_pk_mul_f32 / v_pk_fma_f32 (VOP3P) via inline asm with op_sel/neg
// modifiers: 2 instructions per complex mul/mad instead of 4 scalar.
typedef float f32x2 __attribute__((ext_vector_type(2)));
typedef f32x2 cplx;

// t = (a.lo*b.lo, a.lo*b.hi)   -- broadcast a.lo
__device__ __forceinline__ cplx pk_bcastlo_mul(cplx a, cplx b){
  cplx t;
  asm("v_pk_mul_f32 %0, %1, %2 op_sel:[0,0] op_sel_hi:[0,1]"
      : "=v"(t) : "v"(a), "v"(b));
  return t;
}
// d = (t.lo - a.hi*b.hi, t.hi + a.hi*b.lo)   -- the "i*" cross term
__device__ __forceinline__ cplx pk_cross_mad(cplx a, cplx b, cplx t){
  cplx d;
  asm("v_pk_fma_f32 %0, %1, %2, %3 op_sel:[1,1,0] op_sel_hi:[1,0,1] neg_lo:[0,1,0]"
      : "=v"(d) : "v"(a), "v"(b), "v"(t));
  return d;
}
// t = (a.lo*b.lo + acc.lo, a.lo*b.hi + acc.hi)
__device__ __forceinline__ cplx pk_bcastlo_mad(cplx a, cplx b, cplx acc){
  cplx t;
  asm("v_pk_fma_f32 %0, %1, %2, %3 op_sel:[0,0,0] op_sel_hi:[0,1,1]"
      : "=v"(t) : "v"(a), "v"(b), "v"(acc));
  return t;
}
// d = (t.lo + cs.hi*p.hi, t.hi - cs.hi*p.lo)   -- rxx cross term (-i*s*p)
__device__ __forceinline__ cplx pk_rxx_cross(cplx cs, cplx p, cplx t){
  cplx d;
  asm("v_pk_fma_f32 %0, %1, %2, %3 op_sel:[1,1,0] op_sel_hi:[1,0,1] neg_hi:[0,1,0]"
      : "=v"(d) : "v"(cs), "v"(p), "v"(t));
  return d;
}

__device__ __forceinline__ cplx cmul(cplx a, cplx b){
  return pk_cross_mad(a, b, pk_bcastlo_mul(a, b));
}
__device__ __forceinline__ cplx cmad(cplx a, cplx b, cplx acc){  // acc + a*b
  return pk_cross_mad(a, b, pk_bcastlo_mad(a, b, acc));
}
// rxx update: c*a - i*s*p, cs = (c, s)
__device__ __forceinline__ cplx rxx_upd(cplx cs, cplx a, cplx p){
  return pk_rxx_cross(cs, p, pk_bcastlo_mul(cs, a));
}

// ======================= conv-matrix setup (fused, per-block into LDS) =======================
__device__ __forceinline__ void rz_gate(cplx* st, float t, int bmask){
  float s, c; sincosf(0.5f*t, &s, &c);
  cplx em = {c, -s}, ep = {c, s};
  for(int k=0;k<4;k++) st[k] = cmul(st[k], (k & bmask) ? ep : em);
}
__device__ __forceinline__ void ry_gate_q(cplx* st, float t){
  float s, c; sincosf(0.5f*t, &s, &c);
  for(int bp=0;bp<2;bp++){
    cplx a0 = st[bp], a1 = st[2+bp];
    st[bp]   = c*a0 - s*a1;
    st[2+bp] = s*a0 + c*a1;
  }
}
__device__ __forceinline__ void u3_gate(cplx* st, const float* p, int onq){
  float th=p[0], ph=p[1], la=p[2];
  float ss,cc,sl,cl,sp,cp,spl,cpl;
  sincosf(0.5f*th,&ss,&cc); sincosf(la,&sl,&cl); sincosf(ph,&sp,&cp); sincosf(ph+la,&spl,&cpl);
  cplx u00={cc,0.f},      u01={-cl*ss,-sl*ss};
  cplx u10={cp*ss,sp*ss}, u11={cpl*cc,spl*cc};
  if(onq){
    for(int bp=0;bp<2;bp++){
      cplx a0=st[bp], a1=st[2+bp];
      st[bp]   = cmad(u01,a1,cmul(u00,a0));
      st[2+bp] = cmad(u11,a1,cmul(u10,a0));
    }
  } else {
    for(int bq=0;bq<2;bq++){
      cplx a0=st[2*bq], a1=st[2*bq+1];
      st[2*bq]   = cmad(u01,a1,cmul(u00,a0));
      st[2*bq+1] = cmad(u11,a1,cmul(u10,a0));
    }
  }
}

// ======================= main kernel =======================
// 16 amplitudes per lane, 16 lanes per element, 4 elements per wave.
// Amplitude i[7:0]; wire w <-> bit (7-w).
// Register index r[3:0] = i[7:4]  (wires 0,1,2,3 -> reg masks 8,4,2,1)
// Lane wires 4..7 use LINEAR lane-xor masks (GF(2)-independent, not 1-hot):
//   m4=1, m5=2, m6=5, m7=13
// so that every mask used in the 4-cycle rxx loop is a SINGLE DPP:
//   m45=3 (quad xor3), m56=7 (half_mirror), m67=8 (row_ror:8), m4=1, m57=15 (mirror)
// Amplitude bits as functions of lane s (solve T*m_w = e_w):
//   b4 = s0^s2, b5 = s1, b6 = s2^s3, b7 = s3
// Composite masks (2 DPP, used once each in convs): m6=5 = half∘xor2, m7=13 = mirror∘xor2

#define DPP_XOR1 0xB1    // quad_perm [1,0,3,2]  == xor 1
#define DPP_XOR2 0x4E    // quad_perm [2,3,0,1]  == xor 2
#define DPP_XOR3 0x1B    // quad_perm [3,2,1,0]  == xor 3
#define DPP_ROR8 0x128   // row_ror:8            == xor 8 within 16-lane row
#define DPP_MIRR 0x140   // row_mirror           == xor 15
#define DPP_HALF 0x141   // row_half_mirror      == xor 7

template<int C>
__device__ __forceinline__ float xdpp(float x){
  return __builtin_bit_cast(float,
    __builtin_amdgcn_mov_dpp(__builtin_bit_cast(int, x), C, 0xF, 0xF, true));
}

enum Sh { SH_X1, SH_X2, SH_X3, SH_R8, SH_HALF, SH_MIRR, SH_M5, SH_M13 };

template<Sh S> __device__ __forceinline__ float shf(float x){
  if      constexpr(S==SH_X1)   return xdpp<DPP_XOR1>(x);                    // xor 1
  else if constexpr(S==SH_X2)   return xdpp<DPP_XOR2>(x);                    // xor 2
  else if constexpr(S==SH_X3)   return xdpp<DPP_XOR3>(x);                    // xor 3
  else if constexpr(S==SH_R8)   return xdpp<DPP_ROR8>(x);                    // xor 8
  else if constexpr(S==SH_HALF) return xdpp<DPP_HALF>(x);                    // xor 7
  else if constexpr(S==SH_MIRR) return xdpp<DPP_MIRR>(x);                    // xor 15
  else if constexpr(S==SH_M5)   return xdpp<DPP_HALF>(xdpp<DPP_XOR2>(x));    // xor 7∘2 = 5
  else                          return xdpp<DPP_MIRR>(xdpp<DPP_XOR2>(x));    // xor 15∘2 = 13
}
template<Sh S> __device__ __forceinline__ cplx shc(cplx a){
  cplx r; r[0] = shf<S>(a[0]); r[1] = shf<S>(a[1]); return r;
}

// rxx on two register wires
template<int MR>
__device__ __forceinline__ void rxx_reg(cplx* v, cplx cs){
  #pragma unroll
  for(int r=0;r<16;r++){
    int q = r ^ MR;
    if(r > q) continue;
    cplx a = v[r], b = v[q];
    v[r] = rxx_upd(cs, a, b);
    v[q] = rxx_upd(cs, b, a);
  }
}
template<Sh S>
__device__ __forceinline__ void rxx_lane(cplx* v, cplx cs){
  #pragma unroll
  for(int r=0;r<16;r++){
    cplx p = shc<S>(v[r]);
    v[r] = rxx_upd(cs, v[r], p);
  }
}
// pair (3,4): reg mask 1 + lane xor m4=1
__device__ __forceinline__ void rxx_mix34(cplx* v, cplx cs){
  #pragma unroll
  for(int r=0;r<16;r+=2){
    cplx pa = shc<SH_X1>(v[r^1]);
    cplx pb = shc<SH_X1>(v[r]);
    cplx a = v[r], b = v[r^1];
    v[r]   = rxx_upd(cs, a, pa);
    v[r^1] = rxx_upd(cs, b, pb);
  }
}

// conv on two register wires: group {r, r^MP, r^MQ, r^MQ^MP} = columns 0..3
template<int MQ, int MP>
__device__ __forceinline__ void conv_reg(cplx* v, const cplx* M){
  #pragma unroll
  for(int r=0;r<16;r++){
    if((r & (MQ|MP)) != 0) continue;
    cplx a0=v[r], a1=v[r^MP], a2=v[r^MQ], a3=v[r^MQ^MP];
    v[r]        = cmad(M[3], a3, cmad(M[2], a2, cmad(M[1], a1, cmul(M[0], a0))));
    v[r^MP]     = cmad(M[7], a3, cmad(M[6], a2, cmad(M[5], a1, cmul(M[4], a0))));
    v[r^MQ]     = cmad(M[11],a3, cmad(M[10],a2, cmad(M[9], a1, cmul(M[8], a0))));
    v[r^MQ^MP]  = cmad(M[15],a3, cmad(M[14],a2, cmad(M[13],a1, cmul(M[12],a0))));
  }
}

// conv on two lane wires; k = 2*bit_q + bit_p (per-lane, r-independent)
// SQ flips wire q (mask m_q), SP flips wire p (m_p), SB flips both (m_q^m_p)
template<Sh SQ, Sh SP, Sh SB>
__device__ __forceinline__ void conv_lane(cplx* v, const cplx* M, int k){
  cplx es = M[k*4 + k], ep = M[k*4 + (k^1)], eq = M[k*4 + (k^2)], eb = M[k*4 + (k^3)];
  #pragma unroll
  for(int r=0;r<16;r++){
    cplx pq = shc<SQ>(v[r]);
    cplx pp = shc<SP>(v[r]);
    cplx pb = shc<SB>(v[r]);
    v[r] = cmad(eb, pb, cmad(eq, pq, cmad(ep, pp, cmul(es, v[r]))));
  }
}

// conv (5,3): q = wire5 (lane mask m5=2, xor2 DPP), p = wire3 (reg bit 0)
__device__ __forceinline__ void conv_53(cplx* v, const cplx* M, int b5){
  int t = 2*b5, u = 2 - t;
  const cplx* r0 = M + t*4;        // row k = t   (held bp=0)
  const cplx* r1 = M + (t+1)*4;    // row k = t+1 (held bp=1)
  cplx e00=r0[t], e01=r0[t+1], e02=r0[u], e03=r0[u+1];
  cplx e10=r1[t], e11=r1[t+1], e12=r1[u], e13=r1[u+1];
  #pragma unroll
  for(int r=0;r<16;r+=2){
    cplx pv0 = shc<SH_X2>(v[r]);       // partner (q flipped) of bp=0
    cplx pv1 = shc<SH_X2>(v[r+1]);     // partner of bp=1
    cplx a0 = v[r], a1 = v[r+1];
    v[r]   = cmad(e03, pv1, cmad(e02, pv0, cmad(e01, a1, cmul(e00, a0))));
    v[r+1] = cmad(e13, pv1, cmad(e12, pv0, cmad(e11, a1, cmul(e10, a0))));
  }
}

__global__ void __launch_bounds__(256) qcnn_kernel(
    const float* __restrict__ theta, const float* __restrict__ phi,
    const float* __restrict__ rz, const float* __restrict__ ry,
    const float* __restrict__ u3,
    const float* __restrict__ w1, const float* __restrict__ b1,
    const float* __restrict__ w2, const float* __restrict__ b2,
    float* __restrict__ out){
  __shared__ cplx Msh[112];

  int tid  = threadIdx.x;

  // ---- fused setup: first 28 threads build the 7 folded conv matrices in LDS ----
  if(tid < 28){
    int ci = tid >> 2, col = tid & 3;
    const float* rz3 = rz + 3*ci;
    const float* ry2 = ry + 2*ci;
    int u3slot = 0, u3idx = 0;
    if(ci <= 3){ u3slot = 1; u3idx = ci; }
    else if(ci == 5){ u3slot = 1; u3idx = 5; }
    else if(ci == 6){ u3slot = 2; u3idx = 4; }
    cplx st[4];
    for(int k=0;k<4;k++){ cplx z = {k==col ? 1.f : 0.f, 0.f}; st[k] = z; }
    rz_gate(st, rz3[0], 2);
    { cplx tmp=st[2]; st[2]=st[3]; st[3]=tmp; }
    rz_gate(st, rz3[1], 1);
    ry_gate_q(st, ry2[0]);
    { cplx tmp=st[1]; st[1]=st[3]; st[3]=tmp; }
    ry_gate_q(st, ry2[1]);
    { cplx tmp=st[2]; st[2]=st[3]; st[3]=tmp; }
    rz_gate(st, rz3[2], 1);
    if(u3slot == 1)      u3_gate(st, u3+3*u3idx, 1);
    else if(u3slot == 2) u3_gate(st, u3+3*u3idx, 0);
    for(int k=0;k<4;k++) Msh[ci*16 + k*4 + col] = st[k];
  }
  __syncthreads();

  // ---- main body ----
  int s_   = tid & 15;                       // sublane within element (DPP-row aligned)
  int b    = blockIdx.x*16 + (tid >> 4);     // element id
  int s0 = s_&1, s1 = (s_>>1)&1, s2 = (s_>>2)&1, s3 = (s_>>3)&1;
  // amplitude bits held by this lane (linear code):
  int b4 = s0 ^ s2, b5 = s1, b6 = s2 ^ s3, b7 = s3;

  float th = theta[b], ph = phi[b];
  float c, s;
  __sincosf(th, &s, &c);
  cplx cs = {c, s};

  // zphase factors: cis(phi*(2*(popc_amp) - 8)); lane base = b4+b5+b6+b7
  cplx zp[5];
  {
    int base = b4 + b5 + b6 + b7;
    float a0 = ph * (float)(2*base - 8);
    float sa, ca, s2p, c2p;
    __sincosf(a0, &sa, &ca);
    __sincosf(2.f*ph, &s2p, &c2p);
    cplx step = {c2p, s2p};
    cplx z0 = {ca, sa};
    zp[0] = z0;
    #pragma unroll
    for(int j=1;j<5;j++) zp[j] = cmul(zp[j-1], step);
  }

  // H^8 |0> with cycle-0 zphase folded into the init
  cplx v[16];
  #pragma unroll
  for(int r=0;r<16;r++) v[r] = 0.0625f * zp[__popc(r)];

  #pragma unroll 1
  for(int cyc=0;cyc<4;cyc++){
    if(cyc){
      #pragma unroll
      for(int r=0;r<16;r++) v[r] = cmul(v[r], zp[__popc(r)]);
    }
    // even pairs
    rxx_reg<12>(v, cs);          // (0,1): reg bits 3,2
    rxx_reg<3>(v, cs);           // (2,3): reg bits 1,0
    rxx_lane<SH_X3>(v, cs);      // (4,5): lane mask m45 = 3   (single DPP)
    rxx_lane<SH_R8>(v, cs);      // (6,7): lane mask m67 = 8   (single DPP)
    // odd pairs
    rxx_reg<6>(v, cs);           // (1,2): reg bits 2,1
    rxx_mix34(v, cs);            // (3,4): reg bit0 + lane m4 = 1
    rxx_lane<SH_HALF>(v, cs);    // (5,6): lane mask m56 = 7   (single DPP)
  }

  // convs (U3s folded in by setup)
  conv_reg<4,8>(v, Msh +  0);                                   // (1,0)
  conv_reg<1,2>(v, Msh + 16);                                   // (3,2)
  conv_lane<SH_X2,SH_X1,SH_X3>(Msh ? v : v, Msh + 32, 2*b5 + b4);   // (5,4): m5=2, m4=1, m45=3
  conv_lane<SH_M13,SH_M5,SH_R8>(v, Msh + 48, 2*b7 + b6);        // (7,6): m7=13, m6=5, m67=8
  conv_reg<1,4>(v, Msh + 64);                                   // (3,1)
  conv_lane<SH_M13,SH_X2,SH_MIRR>(v, Msh + 80, 2*b7 + b5);      // (7,5): m7=13, m5=2, m57=15
  conv_53(v, Msh + 96, b5);                                     // (5,3): m5=2

  // <Z_3> = sign from r bit0 ; <Z_7> = sign from amplitude bit b7 = s3
  float tot = 0.f, z3 = 0.f;
  #pragma unroll
  for(int r=0;r<16;r++){
    float m = fmaf(v[r][0], v[r][0], v[r][1]*v[r][1]);
    tot += m;
    z3 += (r & 1) ? -m : m;
  }
  float z7 = b7 ? -tot : tot;
  // xor-reduce over the 16 lanes: masks {1,2,7,8} generate the full group
  z3 += xdpp<DPP_XOR1>(z3);  z7 += xdpp<DPP_XOR1>(z7);
  z3 += xdpp<DPP_XOR2>(z3);  z7 += xdpp<DPP_XOR2>(z7);
  z3 += xdpp<DPP_HALF>(z3);  z7 += xdpp<DPP_HALF>(z7);
  z3 += xdpp<DPP_ROR8>(z3);  z7 += xdpp<DPP_ROR8>(z7);

  // MLP tail, parallelized: lane j<10 computes neuron j, butterfly-sum
  float acc = 0.f;
  if(s_ < 10){
    float hv = tanhf(z3*w1[2*s_] + z7*w1[2*s_+1] + b1[s_]);
    acc = hv * w2[s_];
  }
  acc += xdpp<DPP_XOR1>(acc);
  acc += xdpp<DPP_XOR2>(acc);
  acc += xdpp<DPP_HALF>(acc);
  acc += xdpp<DPP_ROR8>(acc);

  if(s_ == 0){
    float a = acc + b2[0];
    out[b] = 1.f / (1.f + __expf(-a));
  }
}

extern "C" void kernel_launch(void* const* d_in, const int* in_sizes, int n_in,
                              void* d_out, int out_size, void* d_ws, size_t ws_size,
                              hipStream_t stream) {
  const float* theta = (const float*)d_in[0];
  const float* phi   = (const float*)d_in[1];
  const float* rz    = (const float*)d_in[2];
  const float* ry    = (const float*)d_in[3];
  const float* u3    = (const float*)d_in[4];
  const float* w1    = (const float*)d_in[5];
  const float* b1    = (const float*)d_in[6];
  const float* w2    = (const float*)d_in[7];
  const float* b2    = (const float*)d_in[8];

  hipLaunchKernelGGL(qcnn_kernel, dim3(8192/16), dim3(256), 0, stream,
                     theta, phi, rz, ry, u3, w1, b1, w2, b2, (float*)d_out);
}